// Round 13
// baseline (217.015 us; speedup 1.0000x reference)
//
#include <hip/hip_runtime.h>

static inline int ceil_div(long long a, long long b) { return (int)((a + b - 1) / b); }

// Node-range binning: bin = dst >> 8 (256 nodes per bin). N <= 131072 assumed (N=100000).
#define RBITS 8
#define RNODES 256
#define CNT_BLOCKS 96

typedef __attribute__((ext_vector_type(8))) short bf16x8;
typedef __attribute__((ext_vector_type(4))) float f32x4;

// bf16 helpers: pack with round-to-nearest-even, unpack via bit ops
__device__ inline unsigned f2bf(float f) {
    unsigned u = __float_as_uint(f);
    return (u + 0x7fffu + ((u >> 16) & 1u)) >> 16;
}
__device__ inline unsigned pack2(float a, float b) { return f2bf(a) | (f2bf(b) << 16); }
__device__ inline float bf2f(unsigned v) { return __uint_as_float(v << 16); }
__device__ inline float bf_lo(unsigned v) { return __uint_as_float(v << 16); }
__device__ inline float bf_hi(unsigned v) { return __uint_as_float(v & 0xffff0000u); }

// accumulate one edge-record's contribution from a gathered uint4 (8 bf16 ch)
#define ACC8(acc, n, v)                      \
    do {                                     \
        acc[0] += (n) * bf_lo((v).x);        \
        acc[1] += (n) * bf_hi((v).x);        \
        acc[2] += (n) * bf_lo((v).y);        \
        acc[3] += (n) * bf_hi((v).y);        \
        acc[4] += (n) * bf_lo((v).z);        \
        acc[5] += (n) * bf_hi((v).z);        \
        acc[6] += (n) * bf_lo((v).w);        \
        acc[7] += (n) * bf_hi((v).w);        \
    } while (0)

#define EWN(e) __uint_as_float(((e) & 0x7fffu) << 16)

// ---------------- step 1: per-bin edge counts, atomic-free ----------------
__global__ void bin_count(const int* __restrict__ dst, int* __restrict__ hist_g,
                          int NB, int E) {
    __shared__ int hist[512];
    int t = threadIdx.x;
    hist[t] = 0;
    __syncthreads();
    int nvec = E >> 2;
    const int4* d4 = (const int4*)dst;
    for (int v = blockIdx.x * 512 + t; v < nvec; v += CNT_BLOCKS * 512) {
        int4 d = d4[v];
        atomicAdd(&hist[d.x >> RBITS], 1);
        atomicAdd(&hist[d.y >> RBITS], 1);
        atomicAdd(&hist[d.z >> RBITS], 1);
        atomicAdd(&hist[d.w >> RBITS], 1);
    }
    if (blockIdx.x == 0 && t < (E & 3))
        atomicAdd(&hist[dst[(nvec << 2) + t] >> RBITS], 1);
    __syncthreads();
    if (t < NB) hist_g[blockIdx.x * NB + t] = hist[t];
}

// ---------------- step 2: reduce partials + exclusive scan + cursor init ----------------
__global__ void bin_scan(const int* __restrict__ hist_g, int* __restrict__ bin_start,
                         int* __restrict__ bin_cursor, int NB) {
    __shared__ int s[512];
    int t = threadIdx.x;
    int v = 0;
    if (t < NB) {
        for (int k = 0; k < CNT_BLOCKS; ++k) v += hist_g[k * NB + t];
        bin_cursor[t] = 0;
    }
    s[t] = v;
    __syncthreads();
    for (int d = 1; d < 512; d <<= 1) {
        int a = (t >= d) ? s[t - d] : 0;
        __syncthreads();
        s[t] += a;
        __syncthreads();
    }
    if (t < NB) bin_start[t] = s[t] - v;       // exclusive
    if (t == NB - 1) bin_start[NB] = s[t];     // total = E
}

// ---------------- step 3: partition edges into bins (LDS staging) ----------------
#define SC_T 512
#define SC_K 8
#define SC_E (SC_T * SC_K)   // 4096 edges per block
__global__ void bin_scatter(const int* __restrict__ src, const int* __restrict__ dst,
                            const float* __restrict__ w, int* __restrict__ bin_cursor,
                            const int* __restrict__ bin_start,
                            int* __restrict__ bp, float* __restrict__ bw,
                            int NB, int E) {
    __shared__ int hist[512];
    __shared__ int offs[512];               // inclusive scan of hist
    __shared__ int base[512];               // global write base per bin
    __shared__ int stage_p[SC_E];
    __shared__ float stage_w[SC_E];
    __shared__ unsigned short stage_b[SC_E]; // bin id per staged slot
    int t = threadIdx.x;
    hist[t] = 0;
    __syncthreads();
    int e0 = blockIdx.x * SC_E;
    int nE = E - e0; if (nE > SC_E) nE = SC_E;

    int myBin[SC_K], myRank[SC_K], myPack[SC_K];
    float myW[SC_K];
#pragma unroll
    for (int k = 0; k < SC_K; ++k) {
        int idx = t + k * SC_T;
        if (idx < nE) {
            int e = e0 + idx;
            int d = dst[e];
            int b = d >> RBITS;
            myBin[k] = b;
            myPack[k] = (src[e] << RBITS) | (d & (RNODES - 1));
            myW[k] = w[e];
            myRank[k] = atomicAdd(&hist[b], 1);
        }
    }
    __syncthreads();
    offs[t] = hist[t];
    __syncthreads();
    for (int d = 1; d < 512; d <<= 1) {
        int a = (t >= d) ? offs[t - d] : 0;
        __syncthreads();
        offs[t] += a;
        __syncthreads();
    }
    if (t < NB && hist[t]) base[t] = bin_start[t] + atomicAdd(&bin_cursor[t], hist[t]);
#pragma unroll
    for (int k = 0; k < SC_K; ++k) {
        int idx = t + k * SC_T;
        if (idx < nE) {
            int b = myBin[k];
            int pos = (offs[b] - hist[b]) + myRank[k];
            stage_p[pos] = myPack[k];
            stage_w[pos] = myW[k];
            stage_b[pos] = (unsigned short)b;
        }
    }
    __syncthreads();
    for (int p = t; p < nE; p += SC_T) {
        int b = stage_b[p];
        int g = base[b] + (p - (offs[b] - hist[b]));
        bp[g] = stage_p[p];
        bw[g] = stage_w[p];
    }
}

// ---------------- step 4: fused per-bin counting sort -> dinv + dense CSR (4B records) ----
// No LDS staging: pass 2 re-reads bp/bw (L2-hot). LDS = 4KB -> full occupancy.
// ew[e] = (src << 15) | top-15-bits of bf16(w)  (w in (0,1) -> sign bit 0).
__global__ void csr_build(const int* __restrict__ bp, const float* __restrict__ bw,
                          const int* __restrict__ bin_start,
                          int* __restrict__ row_beg, int* __restrict__ row_cnt,
                          float* __restrict__ dinv, unsigned* __restrict__ ew, int N) {
    __shared__ int cnt[RNODES];
    __shared__ float wsum[RNODES];
    __shared__ int starts[RNODES];
    __shared__ int cur[RNODES];
    int b = blockIdx.x;
    int t = threadIdx.x;   // 512
    if (t < RNODES) { cnt[t] = 0; wsum[t] = 0.f; }
    __syncthreads();
    int beg = bin_start[b], end = bin_start[b + 1];
    for (int e = beg + t; e < end; e += 512) {
        int p = bp[e];
        atomicAdd(&cnt[p & (RNODES - 1)], 1);
        atomicAdd(&wsum[p & (RNODES - 1)], bw[e]);
    }
    __syncthreads();
    if (t < RNODES) starts[t] = cnt[t];
    __syncthreads();
    for (int d = 1; d < RNODES; d <<= 1) {
        int a = 0;
        if (t < RNODES && t >= d) a = starts[t - d];
        __syncthreads();
        if (t < RNODES) starts[t] += a;
        __syncthreads();
    }
    if (t < RNODES) {
        int ex = starts[t] - cnt[t];
        cur[t] = beg + ex;
        int node = (b << RBITS) + t;
        if (node < N) {
            row_beg[node] = beg + ex;
            row_cnt[node] = cnt[t];
            dinv[node] = rsqrtf(wsum[t] + 1.0f);   // +1 = self-loop weight
        }
    }
    __syncthreads();
    for (int e = beg + t; e < end; e += 512) {
        int p = bp[e];
        int slot = atomicAdd(&cur[p & (RNODES - 1)], 1);
        ew[slot] = ((unsigned)(p >> RBITS) << 15) | (f2bf(bw[e]) & 0x7fffu);
    }
}

// ---------------- MFMA GEMMs (epilogue scales rows by dinv: table g = dinv * h) ----------------
// G1[N x 64] bf16 = dinv * (X[N x 64] fp32 @ W1)   (split-bf16 3-product)
__global__ __launch_bounds__(256) void gemm1_mfma(const float* __restrict__ X,
                                                  const float* __restrict__ W,
                                                  const float* __restrict__ dinv,
                                                  unsigned short* __restrict__ H, int N) {
    int lane = threadIdx.x & 63;
    int wv = threadIdx.x >> 6;
    int quad = lane >> 4;
    int col = lane & 15;

    bf16x8 Bh[4][2], Bl[4][2];
#pragma unroll
    for (int nt = 0; nt < 4; ++nt)
#pragma unroll
        for (int kh = 0; kh < 2; ++kh)
#pragma unroll
            for (int j = 0; j < 8; ++j) {
                float wval = W[(kh * 32 + quad * 8 + j) * 64 + nt * 16 + col];
                unsigned hb = f2bf(wval);
                Bh[nt][kh][j] = (short)hb;
                Bl[nt][kh][j] = (short)f2bf(wval - bf2f(hb));
            }

#pragma unroll
    for (int rt = 0; rt < 4; ++rt) {
        int rb = blockIdx.x * 256 + wv * 64 + rt * 16;
        if (rb >= N) break;                       // wave-uniform
        int arow = rb + col;
        bf16x8 Ah[2], Al[2];
#pragma unroll
        for (int kh = 0; kh < 2; ++kh) {
            float xv[8];
            if (arow < N) {
                const float4* p = (const float4*)(X + (size_t)arow * 64 + kh * 32 + quad * 8);
                float4 f0 = p[0], f1 = p[1];
                xv[0] = f0.x; xv[1] = f0.y; xv[2] = f0.z; xv[3] = f0.w;
                xv[4] = f1.x; xv[5] = f1.y; xv[6] = f1.z; xv[7] = f1.w;
            } else {
#pragma unroll
                for (int j = 0; j < 8; ++j) xv[j] = 0.f;
            }
#pragma unroll
            for (int j = 0; j < 8; ++j) {
                unsigned hb = f2bf(xv[j]);
                Ah[kh][j] = (short)hb;
                Al[kh][j] = (short)f2bf(xv[j] - bf2f(hb));
            }
        }
        f32x4 acc[4] = {{0,0,0,0},{0,0,0,0},{0,0,0,0},{0,0,0,0}};
#pragma unroll
        for (int nt = 0; nt < 4; ++nt)
#pragma unroll
            for (int kh = 0; kh < 2; ++kh) {
                acc[nt] = __builtin_amdgcn_mfma_f32_16x16x32_bf16(Ah[kh], Bh[nt][kh], acc[nt], 0, 0, 0);
                acc[nt] = __builtin_amdgcn_mfma_f32_16x16x32_bf16(Al[kh], Bh[nt][kh], acc[nt], 0, 0, 0);
                acc[nt] = __builtin_amdgcn_mfma_f32_16x16x32_bf16(Ah[kh], Bl[nt][kh], acc[nt], 0, 0, 0);
            }
        float dval[4];
#pragma unroll
        for (int r = 0; r < 4; ++r) {
            int row = rb + quad * 4 + r;
            dval[r] = (row < N) ? dinv[row] : 0.f;
        }
#pragma unroll
        for (int nt = 0; nt < 4; ++nt)
#pragma unroll
            for (int r = 0; r < 4; ++r) {
                int row = rb + quad * 4 + r;
                if (row < N)
                    H[(size_t)row * 64 + nt * 16 + col] = (unsigned short)f2bf(acc[nt][r] * dval[r]);
            }
    }
}

// G2[N x 32] bf16 = dinv * (Xb[N x 64] bf16 @ W2)   (A exact bf16 -> 2 products)
__global__ __launch_bounds__(256) void gemm2_mfma(const unsigned short* __restrict__ Xb,
                                                  const float* __restrict__ W,
                                                  const float* __restrict__ dinv,
                                                  unsigned short* __restrict__ H, int N) {
    int lane = threadIdx.x & 63;
    int wv = threadIdx.x >> 6;
    int quad = lane >> 4;
    int col = lane & 15;

    bf16x8 Bh[2][2], Bl[2][2];
#pragma unroll
    for (int nt = 0; nt < 2; ++nt)
#pragma unroll
        for (int kh = 0; kh < 2; ++kh)
#pragma unroll
            for (int j = 0; j < 8; ++j) {
                float wval = W[(kh * 32 + quad * 8 + j) * 32 + nt * 16 + col];
                unsigned hb = f2bf(wval);
                Bh[nt][kh][j] = (short)hb;
                Bl[nt][kh][j] = (short)f2bf(wval - bf2f(hb));
            }

#pragma unroll
    for (int rt = 0; rt < 4; ++rt) {
        int rb = blockIdx.x * 256 + wv * 64 + rt * 16;
        if (rb >= N) break;
        int arow = rb + col;
        bf16x8 A[2];
#pragma unroll
        for (int kh = 0; kh < 2; ++kh) {
            if (arow < N) {
                const bf16x8* p = (const bf16x8*)(Xb + (size_t)arow * 64 + kh * 32 + quad * 8);
                A[kh] = *p;                        // already bf16 — exact
            } else {
                A[kh] = bf16x8{0,0,0,0,0,0,0,0};
            }
        }
        f32x4 acc[2] = {{0,0,0,0},{0,0,0,0}};
#pragma unroll
        for (int nt = 0; nt < 2; ++nt)
#pragma unroll
            for (int kh = 0; kh < 2; ++kh) {
                acc[nt] = __builtin_amdgcn_mfma_f32_16x16x32_bf16(A[kh], Bh[nt][kh], acc[nt], 0, 0, 0);
                acc[nt] = __builtin_amdgcn_mfma_f32_16x16x32_bf16(A[kh], Bl[nt][kh], acc[nt], 0, 0, 0);
            }
        float dval[4];
#pragma unroll
        for (int r = 0; r < 4; ++r) {
            int row = rb + quad * 4 + r;
            dval[r] = (row < N) ? dinv[row] : 0.f;
        }
#pragma unroll
        for (int nt = 0; nt < 2; ++nt)
#pragma unroll
            for (int r = 0; r < 4; ++r) {
                int row = rb + quad * 4 + r;
                if (row < N)
                    H[(size_t)row * 32 + nt * 16 + col] = (unsigned short)f2bf(acc[nt][r] * dval[r]);
            }
    }
}

// ---------------- aggregation: 2 nodes per 8-lane group, 4+4 gathers in flight ----------------
// g tables hold dinv*h; out[i] = b + dinv[i]*(g[i] + sum w_e * g[src_e]).
// Layer 1: bf16 g1 in, bf16 relu'd out (feeds gemm2).
__global__ void aggregate64(const unsigned* __restrict__ g, const int* __restrict__ row_beg,
                            const int* __restrict__ row_cnt, const unsigned* __restrict__ ew,
                            const float* __restrict__ dinv, const float* __restrict__ b,
                            unsigned* __restrict__ outb, int N) {
    int t = threadIdx.x;
    int c = t & 7;                        // uint4 index in row (8 ch per lane)
    int i0 = blockIdx.x * 128 + (t >> 3) * 2;   // two consecutive nodes per 8-lane group
    if (i0 >= N) return;
    int i1 = i0 + 1;
    bool hasB = i1 < N;
    int eA = row_beg[i0], endA = eA + row_cnt[i0];
    int eB = hasB ? row_beg[i1] : 0;
    int endB = hasB ? eB + row_cnt[i1] : 0;
    const uint4* h4 = (const uint4*)g;
    float accA[8], accB[8];
#pragma unroll
    for (int j = 0; j < 8; ++j) { accA[j] = 0.f; accB[j] = 0.f; }
    // joint main loop: 4 edges of each node -> 8 independent gathers in flight
    while (eA + 3 < endA && eB + 3 < endB) {
        unsigned a0 = ew[eA], a1 = ew[eA + 1], a2 = ew[eA + 2], a3 = ew[eA + 3];
        unsigned b0 = ew[eB], b1 = ew[eB + 1], b2 = ew[eB + 2], b3 = ew[eB + 3];
        uint4 va0 = h4[(size_t)(a0 >> 15) * 8 + c];
        uint4 va1 = h4[(size_t)(a1 >> 15) * 8 + c];
        uint4 va2 = h4[(size_t)(a2 >> 15) * 8 + c];
        uint4 va3 = h4[(size_t)(a3 >> 15) * 8 + c];
        uint4 vb0 = h4[(size_t)(b0 >> 15) * 8 + c];
        uint4 vb1 = h4[(size_t)(b1 >> 15) * 8 + c];
        uint4 vb2 = h4[(size_t)(b2 >> 15) * 8 + c];
        uint4 vb3 = h4[(size_t)(b3 >> 15) * 8 + c];
        ACC8(accA, EWN(a0), va0); ACC8(accA, EWN(a1), va1);
        ACC8(accA, EWN(a2), va2); ACC8(accA, EWN(a3), va3);
        ACC8(accB, EWN(b0), vb0); ACC8(accB, EWN(b1), vb1);
        ACC8(accB, EWN(b2), vb2); ACC8(accB, EWN(b3), vb3);
        eA += 4; eB += 4;
    }
    // drain A
    for (; eA + 3 < endA; eA += 4) {
        unsigned a0 = ew[eA], a1 = ew[eA + 1], a2 = ew[eA + 2], a3 = ew[eA + 3];
        uint4 va0 = h4[(size_t)(a0 >> 15) * 8 + c];
        uint4 va1 = h4[(size_t)(a1 >> 15) * 8 + c];
        uint4 va2 = h4[(size_t)(a2 >> 15) * 8 + c];
        uint4 va3 = h4[(size_t)(a3 >> 15) * 8 + c];
        ACC8(accA, EWN(a0), va0); ACC8(accA, EWN(a1), va1);
        ACC8(accA, EWN(a2), va2); ACC8(accA, EWN(a3), va3);
    }
    for (; eA < endA; ++eA) {
        unsigned a0 = ew[eA];
        uint4 va0 = h4[(size_t)(a0 >> 15) * 8 + c];
        ACC8(accA, EWN(a0), va0);
    }
    // drain B
    for (; eB + 3 < endB; eB += 4) {
        unsigned b0 = ew[eB], b1 = ew[eB + 1], b2 = ew[eB + 2], b3 = ew[eB + 3];
        uint4 vb0 = h4[(size_t)(b0 >> 15) * 8 + c];
        uint4 vb1 = h4[(size_t)(b1 >> 15) * 8 + c];
        uint4 vb2 = h4[(size_t)(b2 >> 15) * 8 + c];
        uint4 vb3 = h4[(size_t)(b3 >> 15) * 8 + c];
        ACC8(accB, EWN(b0), vb0); ACC8(accB, EWN(b1), vb1);
        ACC8(accB, EWN(b2), vb2); ACC8(accB, EWN(b3), vb3);
    }
    for (; eB < endB; ++eB) {
        unsigned b0 = ew[eB];
        uint4 vb0 = h4[(size_t)(b0 >> 15) * 8 + c];
        ACC8(accB, EWN(b0), vb0);
    }
    // epilogue (relu fused; out feeds gemm2 as bf16)
    const float4* b4 = (const float4*)b;
    float4 bv0 = b4[c * 2];
    float4 bv1 = b4[c * 2 + 1];
    float bb[8] = {bv0.x, bv0.y, bv0.z, bv0.w, bv1.x, bv1.y, bv1.z, bv1.w};
    {
        float di = dinv[i0];
        uint4 hv = h4[(size_t)i0 * 8 + c];
        float hs[8] = {bf_lo(hv.x), bf_hi(hv.x), bf_lo(hv.y), bf_hi(hv.y),
                       bf_lo(hv.z), bf_hi(hv.z), bf_lo(hv.w), bf_hi(hv.w)};
        uint4 ov;
        float o0 = fmaxf(bb[0] + di * (hs[0] + accA[0]), 0.f);
        float o1 = fmaxf(bb[1] + di * (hs[1] + accA[1]), 0.f);
        float o2 = fmaxf(bb[2] + di * (hs[2] + accA[2]), 0.f);
        float o3 = fmaxf(bb[3] + di * (hs[3] + accA[3]), 0.f);
        float o4 = fmaxf(bb[4] + di * (hs[4] + accA[4]), 0.f);
        float o5 = fmaxf(bb[5] + di * (hs[5] + accA[5]), 0.f);
        float o6 = fmaxf(bb[6] + di * (hs[6] + accA[6]), 0.f);
        float o7 = fmaxf(bb[7] + di * (hs[7] + accA[7]), 0.f);
        ov.x = pack2(o0, o1); ov.y = pack2(o2, o3);
        ov.z = pack2(o4, o5); ov.w = pack2(o6, o7);
        ((uint4*)outb)[(size_t)i0 * 8 + c] = ov;
    }
    if (hasB) {
        float di = dinv[i1];
        uint4 hv = h4[(size_t)i1 * 8 + c];
        float hs[8] = {bf_lo(hv.x), bf_hi(hv.x), bf_lo(hv.y), bf_hi(hv.y),
                       bf_lo(hv.z), bf_hi(hv.z), bf_lo(hv.w), bf_hi(hv.w)};
        uint4 ov;
        float o0 = fmaxf(bb[0] + di * (hs[0] + accB[0]), 0.f);
        float o1 = fmaxf(bb[1] + di * (hs[1] + accB[1]), 0.f);
        float o2 = fmaxf(bb[2] + di * (hs[2] + accB[2]), 0.f);
        float o3 = fmaxf(bb[3] + di * (hs[3] + accB[3]), 0.f);
        float o4 = fmaxf(bb[4] + di * (hs[4] + accB[4]), 0.f);
        float o5 = fmaxf(bb[5] + di * (hs[5] + accB[5]), 0.f);
        float o6 = fmaxf(bb[6] + di * (hs[6] + accB[6]), 0.f);
        float o7 = fmaxf(bb[7] + di * (hs[7] + accB[7]), 0.f);
        ov.x = pack2(o0, o1); ov.y = pack2(o2, o3);
        ov.z = pack2(o4, o5); ov.w = pack2(o6, o7);
        ((uint4*)outb)[(size_t)i1 * 8 + c] = ov;
    }
}

// Layer 2: bf16 g2 in, fp32 final out. 2 nodes per 4-lane group.
__global__ void aggregate32(const unsigned* __restrict__ g, const int* __restrict__ row_beg,
                            const int* __restrict__ row_cnt, const unsigned* __restrict__ ew,
                            const float* __restrict__ dinv, const float* __restrict__ b,
                            float* __restrict__ out, int N) {
    int t = threadIdx.x;
    int c = t & 3;                        // uint4 index in row (8 ch per lane)
    int i0 = blockIdx.x * 256 + (t >> 2) * 2;   // two consecutive nodes per 4-lane group
    if (i0 >= N) return;
    int i1 = i0 + 1;
    bool hasB = i1 < N;
    int eA = row_beg[i0], endA = eA + row_cnt[i0];
    int eB = hasB ? row_beg[i1] : 0;
    int endB = hasB ? eB + row_cnt[i1] : 0;
    const uint4* h4 = (const uint4*)g;
    float accA[8], accB[8];
#pragma unroll
    for (int j = 0; j < 8; ++j) { accA[j] = 0.f; accB[j] = 0.f; }
    while (eA + 3 < endA && eB + 3 < endB) {
        unsigned a0 = ew[eA], a1 = ew[eA + 1], a2 = ew[eA + 2], a3 = ew[eA + 3];
        unsigned b0 = ew[eB], b1 = ew[eB + 1], b2 = ew[eB + 2], b3 = ew[eB + 3];
        uint4 va0 = h4[(size_t)(a0 >> 15) * 4 + c];
        uint4 va1 = h4[(size_t)(a1 >> 15) * 4 + c];
        uint4 va2 = h4[(size_t)(a2 >> 15) * 4 + c];
        uint4 va3 = h4[(size_t)(a3 >> 15) * 4 + c];
        uint4 vb0 = h4[(size_t)(b0 >> 15) * 4 + c];
        uint4 vb1 = h4[(size_t)(b1 >> 15) * 4 + c];
        uint4 vb2 = h4[(size_t)(b2 >> 15) * 4 + c];
        uint4 vb3 = h4[(size_t)(b3 >> 15) * 4 + c];
        ACC8(accA, EWN(a0), va0); ACC8(accA, EWN(a1), va1);
        ACC8(accA, EWN(a2), va2); ACC8(accA, EWN(a3), va3);
        ACC8(accB, EWN(b0), vb0); ACC8(accB, EWN(b1), vb1);
        ACC8(accB, EWN(b2), vb2); ACC8(accB, EWN(b3), vb3);
        eA += 4; eB += 4;
    }
    for (; eA + 3 < endA; eA += 4) {
        unsigned a0 = ew[eA], a1 = ew[eA + 1], a2 = ew[eA + 2], a3 = ew[eA + 3];
        uint4 va0 = h4[(size_t)(a0 >> 15) * 4 + c];
        uint4 va1 = h4[(size_t)(a1 >> 15) * 4 + c];
        uint4 va2 = h4[(size_t)(a2 >> 15) * 4 + c];
        uint4 va3 = h4[(size_t)(a3 >> 15) * 4 + c];
        ACC8(accA, EWN(a0), va0); ACC8(accA, EWN(a1), va1);
        ACC8(accA, EWN(a2), va2); ACC8(accA, EWN(a3), va3);
    }
    for (; eA < endA; ++eA) {
        unsigned a0 = ew[eA];
        uint4 va0 = h4[(size_t)(a0 >> 15) * 4 + c];
        ACC8(accA, EWN(a0), va0);
    }
    for (; eB + 3 < endB; eB += 4) {
        unsigned b0 = ew[eB], b1 = ew[eB + 1], b2 = ew[eB + 2], b3 = ew[eB + 3];
        uint4 vb0 = h4[(size_t)(b0 >> 15) * 4 + c];
        uint4 vb1 = h4[(size_t)(b1 >> 15) * 4 + c];
        uint4 vb2 = h4[(size_t)(b2 >> 15) * 4 + c];
        uint4 vb3 = h4[(size_t)(b3 >> 15) * 4 + c];
        ACC8(accB, EWN(b0), vb0); ACC8(accB, EWN(b1), vb1);
        ACC8(accB, EWN(b2), vb2); ACC8(accB, EWN(b3), vb3);
    }
    for (; eB < endB; ++eB) {
        unsigned b0 = ew[eB];
        uint4 vb0 = h4[(size_t)(b0 >> 15) * 4 + c];
        ACC8(accB, EWN(b0), vb0);
    }
    const float4* b4 = (const float4*)b;
    float4 bv0 = b4[c * 2];
    float4 bv1 = b4[c * 2 + 1];
    float bb[8] = {bv0.x, bv0.y, bv0.z, bv0.w, bv1.x, bv1.y, bv1.z, bv1.w};
    {
        float di = dinv[i0];
        uint4 hv = h4[(size_t)i0 * 4 + c];
        float hs[8] = {bf_lo(hv.x), bf_hi(hv.x), bf_lo(hv.y), bf_hi(hv.y),
                       bf_lo(hv.z), bf_hi(hv.z), bf_lo(hv.w), bf_hi(hv.w)};
        float4 o0, o1;
        o0.x = bb[0] + di * (hs[0] + accA[0]);
        o0.y = bb[1] + di * (hs[1] + accA[1]);
        o0.z = bb[2] + di * (hs[2] + accA[2]);
        o0.w = bb[3] + di * (hs[3] + accA[3]);
        o1.x = bb[4] + di * (hs[4] + accA[4]);
        o1.y = bb[5] + di * (hs[5] + accA[5]);
        o1.z = bb[6] + di * (hs[6] + accA[6]);
        o1.w = bb[7] + di * (hs[7] + accA[7]);
        float4* op = (float4*)(out + (size_t)i0 * 32 + c * 8);
        op[0] = o0;
        op[1] = o1;
    }
    if (hasB) {
        float di = dinv[i1];
        uint4 hv = h4[(size_t)i1 * 4 + c];
        float hs[8] = {bf_lo(hv.x), bf_hi(hv.x), bf_lo(hv.y), bf_hi(hv.y),
                       bf_lo(hv.z), bf_hi(hv.z), bf_lo(hv.w), bf_hi(hv.w)};
        float4 o0, o1;
        o0.x = bb[0] + di * (hs[0] + accB[0]);
        o0.y = bb[1] + di * (hs[1] + accB[1]);
        o0.z = bb[2] + di * (hs[2] + accB[2]);
        o0.w = bb[3] + di * (hs[3] + accB[3]);
        o1.x = bb[4] + di * (hs[4] + accB[4]);
        o1.y = bb[5] + di * (hs[5] + accB[5]);
        o1.z = bb[6] + di * (hs[6] + accB[6]);
        o1.w = bb[7] + di * (hs[7] + accB[7]);
        float4* op = (float4*)(out + (size_t)i1 * 32 + c * 8);
        op[0] = o0;
        op[1] = o1;
    }
}

extern "C" void kernel_launch(void* const* d_in, const int* in_sizes, int n_in,
                              void* d_out, int out_size, void* d_ws, size_t ws_size,
                              hipStream_t stream) {
    const float* x  = (const float*)d_in[0];
    const int* eidx = (const int*)d_in[1];      // int64 in reference -> int32 on device
    const float* w  = (const float*)d_in[2];
    const float* W1 = (const float*)d_in[3];
    const float* b1 = (const float*)d_in[4];
    const float* W2 = (const float*)d_in[5];
    const float* b2 = (const float*)d_in[6];
    float* out = (float*)d_out;

    const int E = in_sizes[2];
    const int N = in_sizes[0] / 64;
    const int* src = eidx;
    const int* dst = eidx + E;
    const int NB = ceil_div(N, RNODES);          // 391 bins (must be <= 512)

    // workspace carve-up (256B-aligned)
    char* ws = (char*)d_ws;
    size_t off = 0;
    auto alloc = [&](size_t bytes) -> void* {
        void* p = ws + off;
        off = (off + bytes + 255) & ~(size_t)255;
        return p;
    };
    int*      hist_g     = (int*)alloc((size_t)CNT_BLOCKS * NB * 4);
    int*      bin_cursor = (int*)alloc((size_t)NB * 4);
    int*      bin_start  = (int*)alloc((size_t)(NB + 1) * 4);
    int*      bp         = (int*)alloc((size_t)E * 4);        // binned packed (src<<8)|dstoff
    float*    bw         = (float*)alloc((size_t)E * 4);      // binned weights
    unsigned* ew         = (unsigned*)alloc((size_t)E * 4);   // dense CSR (src<<15)|bf15(w)
    int*      row_beg    = (int*)alloc((size_t)N * 4);
    int*      row_cnt    = (int*)alloc((size_t)N * 4);
    float*    dinv       = (float*)alloc((size_t)N * 4);
    unsigned* g1         = (unsigned*)alloc((size_t)N * 32 * 4);  // bf16 dinv*h1, N x 64
    unsigned* out1b      = (unsigned*)alloc((size_t)N * 32 * 4);  // bf16 relu(out1), N x 64
    unsigned* g2         = (unsigned*)alloc((size_t)N * 16 * 4);  // bf16 dinv*h2, N x 32

    // build (no per-edge global atomics anywhere)
    bin_count<<<CNT_BLOCKS, 512, 0, stream>>>(dst, hist_g, NB, E);
    bin_scan<<<1, 512, 0, stream>>>(hist_g, bin_start, bin_cursor, NB);
    bin_scatter<<<ceil_div(E, SC_E), SC_T, 0, stream>>>(src, dst, w, bin_cursor, bin_start,
                                                        bp, bw, NB, E);
    csr_build<<<NB, 512, 0, stream>>>(bp, bw, bin_start, row_beg, row_cnt, dinv, ew, N);

    // layer 1 (MFMA gemm -> bf16 g1 = dinv*h1; aggregate -> bf16 relu'd out1)
    gemm1_mfma<<<ceil_div(N, 256), 256, 0, stream>>>(x, W1, dinv, (unsigned short*)g1, N);
    aggregate64<<<ceil_div(N, 128), 512, 0, stream>>>(g1, row_beg, row_cnt, ew, dinv, b1, out1b, N);

    // layer 2 (bf16-A MFMA gemm -> bf16 g2 = dinv*h2; aggregate -> fp32 out)
    gemm2_mfma<<<ceil_div(N, 256), 256, 0, stream>>>((const unsigned short*)out1b, W2, dinv,
                                                     (unsigned short*)g2, N);
    aggregate32<<<ceil_div(N, 256), 512, 0, stream>>>(g2, row_beg, row_cnt, ew, dinv, b2, out, N);
}

// Round 14
// 206.682 us; speedup vs baseline: 1.0500x; 1.0500x over previous
//
#include <hip/hip_runtime.h>

static inline int ceil_div(long long a, long long b) { return (int)((a + b - 1) / b); }

// Node-range binning: bin = dst >> 8 (256 nodes per bin). N <= 131072 assumed (N=100000).
#define RBITS 8
#define RNODES 256
#define CNT_BLOCKS 96

typedef __attribute__((ext_vector_type(8))) short bf16x8;
typedef __attribute__((ext_vector_type(4))) float f32x4;

// bf16 helpers: pack with round-to-nearest-even, unpack via bit ops
__device__ inline unsigned f2bf(float f) {
    unsigned u = __float_as_uint(f);
    return (u + 0x7fffu + ((u >> 16) & 1u)) >> 16;
}
__device__ inline unsigned pack2(float a, float b) { return f2bf(a) | (f2bf(b) << 16); }
__device__ inline float bf2f(unsigned v) { return __uint_as_float(v << 16); }
__device__ inline float bf_lo(unsigned v) { return __uint_as_float(v << 16); }
__device__ inline float bf_hi(unsigned v) { return __uint_as_float(v & 0xffff0000u); }

// ---------------- step 1: per-bin edge counts, atomic-free ----------------
__global__ void bin_count(const int* __restrict__ dst, int* __restrict__ hist_g,
                          int NB, int E) {
    __shared__ int hist[512];
    int t = threadIdx.x;
    hist[t] = 0;
    __syncthreads();
    int nvec = E >> 2;
    const int4* d4 = (const int4*)dst;
    for (int v = blockIdx.x * 512 + t; v < nvec; v += CNT_BLOCKS * 512) {
        int4 d = d4[v];
        atomicAdd(&hist[d.x >> RBITS], 1);
        atomicAdd(&hist[d.y >> RBITS], 1);
        atomicAdd(&hist[d.z >> RBITS], 1);
        atomicAdd(&hist[d.w >> RBITS], 1);
    }
    if (blockIdx.x == 0 && t < (E & 3))
        atomicAdd(&hist[dst[(nvec << 2) + t] >> RBITS], 1);
    __syncthreads();
    if (t < NB) hist_g[blockIdx.x * NB + t] = hist[t];
}

// ---------------- step 2: reduce partials + exclusive scan + cursor init ----------------
__global__ void bin_scan(const int* __restrict__ hist_g, int* __restrict__ bin_start,
                         int* __restrict__ bin_cursor, int NB) {
    __shared__ int s[512];
    int t = threadIdx.x;
    int v = 0;
    if (t < NB) {
        for (int k = 0; k < CNT_BLOCKS; ++k) v += hist_g[k * NB + t];
        bin_cursor[t] = 0;
    }
    s[t] = v;
    __syncthreads();
    for (int d = 1; d < 512; d <<= 1) {
        int a = (t >= d) ? s[t - d] : 0;
        __syncthreads();
        s[t] += a;
        __syncthreads();
    }
    if (t < NB) bin_start[t] = s[t] - v;       // exclusive
    if (t == NB - 1) bin_start[NB] = s[t];     // total = E
}

// ---------------- step 3: partition edges into bins (LDS staging) ----------------
#define SC_T 512
#define SC_K 8
#define SC_E (SC_T * SC_K)   // 4096 edges per block
__global__ void bin_scatter(const int* __restrict__ src, const int* __restrict__ dst,
                            const float* __restrict__ w, int* __restrict__ bin_cursor,
                            const int* __restrict__ bin_start,
                            int* __restrict__ bp, float* __restrict__ bw,
                            int NB, int E) {
    __shared__ int hist[512];
    __shared__ int offs[512];               // inclusive scan of hist
    __shared__ int base[512];               // global write base per bin
    __shared__ int stage_p[SC_E];
    __shared__ float stage_w[SC_E];
    __shared__ unsigned short stage_b[SC_E]; // bin id per staged slot
    int t = threadIdx.x;
    hist[t] = 0;
    __syncthreads();
    int e0 = blockIdx.x * SC_E;
    int nE = E - e0; if (nE > SC_E) nE = SC_E;

    int myBin[SC_K], myRank[SC_K], myPack[SC_K];
    float myW[SC_K];
#pragma unroll
    for (int k = 0; k < SC_K; ++k) {
        int idx = t + k * SC_T;
        if (idx < nE) {
            int e = e0 + idx;
            int d = dst[e];
            int b = d >> RBITS;
            myBin[k] = b;
            myPack[k] = (src[e] << RBITS) | (d & (RNODES - 1));
            myW[k] = w[e];
            myRank[k] = atomicAdd(&hist[b], 1);
        }
    }
    __syncthreads();
    offs[t] = hist[t];
    __syncthreads();
    for (int d = 1; d < 512; d <<= 1) {
        int a = (t >= d) ? offs[t - d] : 0;
        __syncthreads();
        offs[t] += a;
        __syncthreads();
    }
    if (t < NB && hist[t]) base[t] = bin_start[t] + atomicAdd(&bin_cursor[t], hist[t]);
#pragma unroll
    for (int k = 0; k < SC_K; ++k) {
        int idx = t + k * SC_T;
        if (idx < nE) {
            int b = myBin[k];
            int pos = (offs[b] - hist[b]) + myRank[k];
            stage_p[pos] = myPack[k];
            stage_w[pos] = myW[k];
            stage_b[pos] = (unsigned short)b;
        }
    }
    __syncthreads();
    for (int p = t; p < nE; p += SC_T) {
        int b = stage_b[p];
        int g = base[b] + (p - (offs[b] - hist[b]));
        bp[g] = stage_p[p];
        bw[g] = stage_w[p];
    }
}

// ---------------- step 4: fused per-bin counting sort -> dinv + dense CSR (4B records) ----
// No LDS staging: pass 2 re-reads bp/bw (L2-hot). LDS = 4KB -> full occupancy.
// ew[e] = (src << 15) | top-15-bits of bf16(w)  (w in (0,1) -> sign bit 0).
__global__ void csr_build(const int* __restrict__ bp, const float* __restrict__ bw,
                          const int* __restrict__ bin_start,
                          int* __restrict__ row_beg, int* __restrict__ row_cnt,
                          float* __restrict__ dinv, unsigned* __restrict__ ew, int N) {
    __shared__ int cnt[RNODES];
    __shared__ float wsum[RNODES];
    __shared__ int starts[RNODES];
    __shared__ int cur[RNODES];
    int b = blockIdx.x;
    int t = threadIdx.x;   // 512
    if (t < RNODES) { cnt[t] = 0; wsum[t] = 0.f; }
    __syncthreads();
    int beg = bin_start[b], end = bin_start[b + 1];
    for (int e = beg + t; e < end; e += 512) {
        int p = bp[e];
        atomicAdd(&cnt[p & (RNODES - 1)], 1);
        atomicAdd(&wsum[p & (RNODES - 1)], bw[e]);
    }
    __syncthreads();
    if (t < RNODES) starts[t] = cnt[t];
    __syncthreads();
    for (int d = 1; d < RNODES; d <<= 1) {
        int a = 0;
        if (t < RNODES && t >= d) a = starts[t - d];
        __syncthreads();
        if (t < RNODES) starts[t] += a;
        __syncthreads();
    }
    if (t < RNODES) {
        int ex = starts[t] - cnt[t];
        cur[t] = beg + ex;
        int node = (b << RBITS) + t;
        if (node < N) {
            row_beg[node] = beg + ex;
            row_cnt[node] = cnt[t];
            dinv[node] = rsqrtf(wsum[t] + 1.0f);   // +1 = self-loop weight
        }
    }
    __syncthreads();
    for (int e = beg + t; e < end; e += 512) {
        int p = bp[e];
        int slot = atomicAdd(&cur[p & (RNODES - 1)], 1);
        ew[slot] = ((unsigned)(p >> RBITS) << 15) | (f2bf(bw[e]) & 0x7fffu);
    }
}

// ---------------- MFMA GEMMs (epilogue scales rows by dinv: table g = dinv * h) ----------------
// G1[N x 64] bf16 = dinv * (X[N x 64] fp32 @ W1)   (split-bf16 3-product)
__global__ __launch_bounds__(256) void gemm1_mfma(const float* __restrict__ X,
                                                  const float* __restrict__ W,
                                                  const float* __restrict__ dinv,
                                                  unsigned short* __restrict__ H, int N) {
    int lane = threadIdx.x & 63;
    int wv = threadIdx.x >> 6;
    int quad = lane >> 4;
    int col = lane & 15;

    bf16x8 Bh[4][2], Bl[4][2];
#pragma unroll
    for (int nt = 0; nt < 4; ++nt)
#pragma unroll
        for (int kh = 0; kh < 2; ++kh)
#pragma unroll
            for (int j = 0; j < 8; ++j) {
                float wval = W[(kh * 32 + quad * 8 + j) * 64 + nt * 16 + col];
                unsigned hb = f2bf(wval);
                Bh[nt][kh][j] = (short)hb;
                Bl[nt][kh][j] = (short)f2bf(wval - bf2f(hb));
            }

#pragma unroll
    for (int rt = 0; rt < 4; ++rt) {
        int rb = blockIdx.x * 256 + wv * 64 + rt * 16;
        if (rb >= N) break;                       // wave-uniform
        int arow = rb + col;
        bf16x8 Ah[2], Al[2];
#pragma unroll
        for (int kh = 0; kh < 2; ++kh) {
            float xv[8];
            if (arow < N) {
                const float4* p = (const float4*)(X + (size_t)arow * 64 + kh * 32 + quad * 8);
                float4 f0 = p[0], f1 = p[1];
                xv[0] = f0.x; xv[1] = f0.y; xv[2] = f0.z; xv[3] = f0.w;
                xv[4] = f1.x; xv[5] = f1.y; xv[6] = f1.z; xv[7] = f1.w;
            } else {
#pragma unroll
                for (int j = 0; j < 8; ++j) xv[j] = 0.f;
            }
#pragma unroll
            for (int j = 0; j < 8; ++j) {
                unsigned hb = f2bf(xv[j]);
                Ah[kh][j] = (short)hb;
                Al[kh][j] = (short)f2bf(xv[j] - bf2f(hb));
            }
        }
        f32x4 acc[4] = {{0,0,0,0},{0,0,0,0},{0,0,0,0},{0,0,0,0}};
#pragma unroll
        for (int nt = 0; nt < 4; ++nt)
#pragma unroll
            for (int kh = 0; kh < 2; ++kh) {
                acc[nt] = __builtin_amdgcn_mfma_f32_16x16x32_bf16(Ah[kh], Bh[nt][kh], acc[nt], 0, 0, 0);
                acc[nt] = __builtin_amdgcn_mfma_f32_16x16x32_bf16(Al[kh], Bh[nt][kh], acc[nt], 0, 0, 0);
                acc[nt] = __builtin_amdgcn_mfma_f32_16x16x32_bf16(Ah[kh], Bl[nt][kh], acc[nt], 0, 0, 0);
            }
        float dval[4];
#pragma unroll
        for (int r = 0; r < 4; ++r) {
            int row = rb + quad * 4 + r;
            dval[r] = (row < N) ? dinv[row] : 0.f;
        }
#pragma unroll
        for (int nt = 0; nt < 4; ++nt)
#pragma unroll
            for (int r = 0; r < 4; ++r) {
                int row = rb + quad * 4 + r;
                if (row < N)
                    H[(size_t)row * 64 + nt * 16 + col] = (unsigned short)f2bf(acc[nt][r] * dval[r]);
            }
    }
}

// G2[N x 32] bf16 = dinv * (Xb[N x 64] bf16 @ W2)   (A exact bf16 -> 2 products)
__global__ __launch_bounds__(256) void gemm2_mfma(const unsigned short* __restrict__ Xb,
                                                  const float* __restrict__ W,
                                                  const float* __restrict__ dinv,
                                                  unsigned short* __restrict__ H, int N) {
    int lane = threadIdx.x & 63;
    int wv = threadIdx.x >> 6;
    int quad = lane >> 4;
    int col = lane & 15;

    bf16x8 Bh[2][2], Bl[2][2];
#pragma unroll
    for (int nt = 0; nt < 2; ++nt)
#pragma unroll
        for (int kh = 0; kh < 2; ++kh)
#pragma unroll
            for (int j = 0; j < 8; ++j) {
                float wval = W[(kh * 32 + quad * 8 + j) * 32 + nt * 16 + col];
                unsigned hb = f2bf(wval);
                Bh[nt][kh][j] = (short)hb;
                Bl[nt][kh][j] = (short)f2bf(wval - bf2f(hb));
            }

#pragma unroll
    for (int rt = 0; rt < 4; ++rt) {
        int rb = blockIdx.x * 256 + wv * 64 + rt * 16;
        if (rb >= N) break;
        int arow = rb + col;
        bf16x8 A[2];
#pragma unroll
        for (int kh = 0; kh < 2; ++kh) {
            if (arow < N) {
                const bf16x8* p = (const bf16x8*)(Xb + (size_t)arow * 64 + kh * 32 + quad * 8);
                A[kh] = *p;                        // already bf16 — exact
            } else {
                A[kh] = bf16x8{0,0,0,0,0,0,0,0};
            }
        }
        f32x4 acc[2] = {{0,0,0,0},{0,0,0,0}};
#pragma unroll
        for (int nt = 0; nt < 2; ++nt)
#pragma unroll
            for (int kh = 0; kh < 2; ++kh) {
                acc[nt] = __builtin_amdgcn_mfma_f32_16x16x32_bf16(A[kh], Bh[nt][kh], acc[nt], 0, 0, 0);
                acc[nt] = __builtin_amdgcn_mfma_f32_16x16x32_bf16(A[kh], Bl[nt][kh], acc[nt], 0, 0, 0);
            }
        float dval[4];
#pragma unroll
        for (int r = 0; r < 4; ++r) {
            int row = rb + quad * 4 + r;
            dval[r] = (row < N) ? dinv[row] : 0.f;
        }
#pragma unroll
        for (int nt = 0; nt < 2; ++nt)
#pragma unroll
            for (int r = 0; r < 4; ++r) {
                int row = rb + quad * 4 + r;
                if (row < N)
                    H[(size_t)row * 32 + nt * 16 + col] = (unsigned short)f2bf(acc[nt][r] * dval[r]);
            }
    }
}

// ---------------- aggregation: 1 node per 8-lane group, 4x unrolled, 4B edge records ------
// g tables hold dinv*h; out[i] = b + dinv[i]*(g[i] + sum w_e * g[src_e]).
// Layer 1: bf16 g1 in, bf16 relu'd out (feeds gemm2).
__global__ void aggregate64(const unsigned* __restrict__ g, const int* __restrict__ row_beg,
                            const int* __restrict__ row_cnt, const unsigned* __restrict__ ew,
                            const float* __restrict__ dinv, const float* __restrict__ b,
                            unsigned* __restrict__ outb, int N) {
    int t = threadIdx.x;
    int c = t & 7;                       // uint4 index in row (8 ch per lane)
    int i = blockIdx.x * 64 + (t >> 3);  // node per 8-lane group
    if (i >= N) return;
    int e = row_beg[i];
    int end = e + row_cnt[i];
    const uint4* h4 = (const uint4*)g;
    float acc[8];
#pragma unroll
    for (int j = 0; j < 8; ++j) acc[j] = 0.f;
    for (; e + 3 < end; e += 4) {
        unsigned e0 = ew[e], e1 = ew[e + 1], e2 = ew[e + 2], e3 = ew[e + 3];
        float n0 = __uint_as_float((e0 & 0x7fffu) << 16);
        float n1 = __uint_as_float((e1 & 0x7fffu) << 16);
        float n2 = __uint_as_float((e2 & 0x7fffu) << 16);
        float n3 = __uint_as_float((e3 & 0x7fffu) << 16);
        uint4 v0 = h4[(size_t)(e0 >> 15) * 8 + c];
        uint4 v1 = h4[(size_t)(e1 >> 15) * 8 + c];
        uint4 v2 = h4[(size_t)(e2 >> 15) * 8 + c];
        uint4 v3 = h4[(size_t)(e3 >> 15) * 8 + c];
        acc[0] += n0 * bf_lo(v0.x) + n1 * bf_lo(v1.x) + n2 * bf_lo(v2.x) + n3 * bf_lo(v3.x);
        acc[1] += n0 * bf_hi(v0.x) + n1 * bf_hi(v1.x) + n2 * bf_hi(v2.x) + n3 * bf_hi(v3.x);
        acc[2] += n0 * bf_lo(v0.y) + n1 * bf_lo(v1.y) + n2 * bf_lo(v2.y) + n3 * bf_lo(v3.y);
        acc[3] += n0 * bf_hi(v0.y) + n1 * bf_hi(v1.y) + n2 * bf_hi(v2.y) + n3 * bf_hi(v3.y);
        acc[4] += n0 * bf_lo(v0.z) + n1 * bf_lo(v1.z) + n2 * bf_lo(v2.z) + n3 * bf_lo(v3.z);
        acc[5] += n0 * bf_hi(v0.z) + n1 * bf_hi(v1.z) + n2 * bf_hi(v2.z) + n3 * bf_hi(v3.z);
        acc[6] += n0 * bf_lo(v0.w) + n1 * bf_lo(v1.w) + n2 * bf_lo(v2.w) + n3 * bf_lo(v3.w);
        acc[7] += n0 * bf_hi(v0.w) + n1 * bf_hi(v1.w) + n2 * bf_hi(v2.w) + n3 * bf_hi(v3.w);
    }
    for (; e < end; ++e) {
        unsigned e0 = ew[e];
        float n0 = __uint_as_float((e0 & 0x7fffu) << 16);
        uint4 v0 = h4[(size_t)(e0 >> 15) * 8 + c];
        acc[0] += n0 * bf_lo(v0.x);
        acc[1] += n0 * bf_hi(v0.x);
        acc[2] += n0 * bf_lo(v0.y);
        acc[3] += n0 * bf_hi(v0.y);
        acc[4] += n0 * bf_lo(v0.z);
        acc[5] += n0 * bf_hi(v0.z);
        acc[6] += n0 * bf_lo(v0.w);
        acc[7] += n0 * bf_hi(v0.w);
    }
    float di = dinv[i];
    uint4 hv = h4[(size_t)i * 8 + c];
    float hs[8] = {bf_lo(hv.x), bf_hi(hv.x), bf_lo(hv.y), bf_hi(hv.y),
                   bf_lo(hv.z), bf_hi(hv.z), bf_lo(hv.w), bf_hi(hv.w)};
    float4 b0 = ((const float4*)b)[c * 2];
    float4 b1 = ((const float4*)b)[c * 2 + 1];
    float o[8];
    o[0] = b0.x + di * (hs[0] + acc[0]);
    o[1] = b0.y + di * (hs[1] + acc[1]);
    o[2] = b0.z + di * (hs[2] + acc[2]);
    o[3] = b0.w + di * (hs[3] + acc[3]);
    o[4] = b1.x + di * (hs[4] + acc[4]);
    o[5] = b1.y + di * (hs[5] + acc[5]);
    o[6] = b1.z + di * (hs[6] + acc[6]);
    o[7] = b1.w + di * (hs[7] + acc[7]);
#pragma unroll
    for (int j = 0; j < 8; ++j) o[j] = fmaxf(o[j], 0.f);   // fused relu (out1 only feeds gemm2)
    uint4 ov;
    ov.x = pack2(o[0], o[1]);
    ov.y = pack2(o[2], o[3]);
    ov.z = pack2(o[4], o[5]);
    ov.w = pack2(o[6], o[7]);
    ((uint4*)outb)[(size_t)i * 8 + c] = ov;
}

// Layer 2: bf16 g2 in, fp32 final out. 1 node per 4-lane group.
__global__ void aggregate32(const unsigned* __restrict__ g, const int* __restrict__ row_beg,
                            const int* __restrict__ row_cnt, const unsigned* __restrict__ ew,
                            const float* __restrict__ dinv, const float* __restrict__ b,
                            float* __restrict__ out, int N) {
    int t = threadIdx.x;
    int c = t & 3;                        // uint4 index in row (8 ch per lane)
    int i = blockIdx.x * 128 + (t >> 2);  // node per 4-lane group
    if (i >= N) return;
    int e = row_beg[i];
    int end = e + row_cnt[i];
    const uint4* h4 = (const uint4*)g;
    float acc[8];
#pragma unroll
    for (int j = 0; j < 8; ++j) acc[j] = 0.f;
    for (; e + 3 < end; e += 4) {
        unsigned e0 = ew[e], e1 = ew[e + 1], e2 = ew[e + 2], e3 = ew[e + 3];
        float n0 = __uint_as_float((e0 & 0x7fffu) << 16);
        float n1 = __uint_as_float((e1 & 0x7fffu) << 16);
        float n2 = __uint_as_float((e2 & 0x7fffu) << 16);
        float n3 = __uint_as_float((e3 & 0x7fffu) << 16);
        uint4 v0 = h4[(size_t)(e0 >> 15) * 4 + c];
        uint4 v1 = h4[(size_t)(e1 >> 15) * 4 + c];
        uint4 v2 = h4[(size_t)(e2 >> 15) * 4 + c];
        uint4 v3 = h4[(size_t)(e3 >> 15) * 4 + c];
        acc[0] += n0 * bf_lo(v0.x) + n1 * bf_lo(v1.x) + n2 * bf_lo(v2.x) + n3 * bf_lo(v3.x);
        acc[1] += n0 * bf_hi(v0.x) + n1 * bf_hi(v1.x) + n2 * bf_hi(v2.x) + n3 * bf_hi(v3.x);
        acc[2] += n0 * bf_lo(v0.y) + n1 * bf_lo(v1.y) + n2 * bf_lo(v2.y) + n3 * bf_lo(v3.y);
        acc[3] += n0 * bf_hi(v0.y) + n1 * bf_hi(v1.y) + n2 * bf_hi(v2.y) + n3 * bf_hi(v3.y);
        acc[4] += n0 * bf_lo(v0.z) + n1 * bf_lo(v1.z) + n2 * bf_lo(v2.z) + n3 * bf_lo(v3.z);
        acc[5] += n0 * bf_hi(v0.z) + n1 * bf_hi(v1.z) + n2 * bf_hi(v2.z) + n3 * bf_hi(v3.z);
        acc[6] += n0 * bf_lo(v0.w) + n1 * bf_lo(v1.w) + n2 * bf_lo(v2.w) + n3 * bf_lo(v3.w);
        acc[7] += n0 * bf_hi(v0.w) + n1 * bf_hi(v1.w) + n2 * bf_hi(v2.w) + n3 * bf_hi(v3.w);
    }
    for (; e < end; ++e) {
        unsigned e0 = ew[e];
        float n0 = __uint_as_float((e0 & 0x7fffu) << 16);
        uint4 v0 = h4[(size_t)(e0 >> 15) * 4 + c];
        acc[0] += n0 * bf_lo(v0.x);
        acc[1] += n0 * bf_hi(v0.x);
        acc[2] += n0 * bf_lo(v0.y);
        acc[3] += n0 * bf_hi(v0.y);
        acc[4] += n0 * bf_lo(v0.z);
        acc[5] += n0 * bf_hi(v0.z);
        acc[6] += n0 * bf_lo(v0.w);
        acc[7] += n0 * bf_hi(v0.w);
    }
    float di = dinv[i];
    uint4 hv = h4[(size_t)i * 4 + c];
    float hs[8] = {bf_lo(hv.x), bf_hi(hv.x), bf_lo(hv.y), bf_hi(hv.y),
                   bf_lo(hv.z), bf_hi(hv.z), bf_lo(hv.w), bf_hi(hv.w)};
    float4 b0 = ((const float4*)b)[c * 2];
    float4 b1 = ((const float4*)b)[c * 2 + 1];
    float4 o0, o1;
    o0.x = b0.x + di * (hs[0] + acc[0]);
    o0.y = b0.y + di * (hs[1] + acc[1]);
    o0.z = b0.z + di * (hs[2] + acc[2]);
    o0.w = b0.w + di * (hs[3] + acc[3]);
    o1.x = b1.x + di * (hs[4] + acc[4]);
    o1.y = b1.y + di * (hs[5] + acc[5]);
    o1.z = b1.z + di * (hs[6] + acc[6]);
    o1.w = b1.w + di * (hs[7] + acc[7]);
    float4* op = (float4*)(out + (size_t)i * 32 + c * 8);
    op[0] = o0;
    op[1] = o1;
}

extern "C" void kernel_launch(void* const* d_in, const int* in_sizes, int n_in,
                              void* d_out, int out_size, void* d_ws, size_t ws_size,
                              hipStream_t stream) {
    const float* x  = (const float*)d_in[0];
    const int* eidx = (const int*)d_in[1];      // int64 in reference -> int32 on device
    const float* w  = (const float*)d_in[2];
    const float* W1 = (const float*)d_in[3];
    const float* b1 = (const float*)d_in[4];
    const float* W2 = (const float*)d_in[5];
    const float* b2 = (const float*)d_in[6];
    float* out = (float*)d_out;

    const int E = in_sizes[2];
    const int N = in_sizes[0] / 64;
    const int* src = eidx;
    const int* dst = eidx + E;
    const int NB = ceil_div(N, RNODES);          // 391 bins (must be <= 512)

    // workspace carve-up (256B-aligned)
    char* ws = (char*)d_ws;
    size_t off = 0;
    auto alloc = [&](size_t bytes) -> void* {
        void* p = ws + off;
        off = (off + bytes + 255) & ~(size_t)255;
        return p;
    };
    int*      hist_g     = (int*)alloc((size_t)CNT_BLOCKS * NB * 4);
    int*      bin_cursor = (int*)alloc((size_t)NB * 4);
    int*      bin_start  = (int*)alloc((size_t)(NB + 1) * 4);
    int*      bp         = (int*)alloc((size_t)E * 4);        // binned packed (src<<8)|dstoff
    float*    bw         = (float*)alloc((size_t)E * 4);      // binned weights
    unsigned* ew         = (unsigned*)alloc((size_t)E * 4);   // dense CSR (src<<15)|bf15(w)
    int*      row_beg    = (int*)alloc((size_t)N * 4);
    int*      row_cnt    = (int*)alloc((size_t)N * 4);
    float*    dinv       = (float*)alloc((size_t)N * 4);
    unsigned* g1         = (unsigned*)alloc((size_t)N * 32 * 4);  // bf16 dinv*h1, N x 64
    unsigned* out1b      = (unsigned*)alloc((size_t)N * 32 * 4);  // bf16 relu(out1), N x 64
    unsigned* g2         = (unsigned*)alloc((size_t)N * 16 * 4);  // bf16 dinv*h2, N x 32

    // build (no per-edge global atomics anywhere)
    bin_count<<<CNT_BLOCKS, 512, 0, stream>>>(dst, hist_g, NB, E);
    bin_scan<<<1, 512, 0, stream>>>(hist_g, bin_start, bin_cursor, NB);
    bin_scatter<<<ceil_div(E, SC_E), SC_T, 0, stream>>>(src, dst, w, bin_cursor, bin_start,
                                                        bp, bw, NB, E);
    csr_build<<<NB, 512, 0, stream>>>(bp, bw, bin_start, row_beg, row_cnt, dinv, ew, N);

    // layer 1 (MFMA gemm -> bf16 g1 = dinv*h1; aggregate -> bf16 relu'd out1)
    gemm1_mfma<<<ceil_div(N, 256), 256, 0, stream>>>(x, W1, dinv, (unsigned short*)g1, N);
    aggregate64<<<ceil_div(N, 64), 512, 0, stream>>>(g1, row_beg, row_cnt, ew, dinv, b1, out1b, N);

    // layer 2 (bf16-A MFMA gemm -> bf16 g2 = dinv*h2; aggregate -> fp32 out)
    gemm2_mfma<<<ceil_div(N, 256), 256, 0, stream>>>((const unsigned short*)out1b, W2, dinv,
                                                     (unsigned short*)g2, N);
    aggregate32<<<ceil_div(N, 128), 512, 0, stream>>>(g2, row_beg, row_cnt, ew, dinv, b2, out, N);
}

// Round 15
// 202.303 us; speedup vs baseline: 1.0727x; 1.0216x over previous
//
#include <hip/hip_runtime.h>

static inline int ceil_div(long long a, long long b) { return (int)((a + b - 1) / b); }

// Node-range binning: bin = dst >> 8 (256 nodes per bin). N <= 131072 assumed (N=100000).
#define RBITS 8
#define RNODES 256
#define CNT_BLOCKS 96

typedef __attribute__((ext_vector_type(8))) short bf16x8;
typedef __attribute__((ext_vector_type(4))) float f32x4;

// bf16 helpers: pack with round-to-nearest-even, unpack via bit ops
__device__ inline unsigned f2bf(float f) {
    unsigned u = __float_as_uint(f);
    return (u + 0x7fffu + ((u >> 16) & 1u)) >> 16;
}
__device__ inline unsigned pack2(float a, float b) { return f2bf(a) | (f2bf(b) << 16); }
__device__ inline float bf2f(unsigned v) { return __uint_as_float(v << 16); }
__device__ inline float bf_lo(unsigned v) { return __uint_as_float(v << 16); }
__device__ inline float bf_hi(unsigned v) { return __uint_as_float(v & 0xffff0000u); }

// ---------------- step 1: per-bin edge counts, atomic-free ----------------
__global__ void bin_count(const int* __restrict__ dst, int* __restrict__ hist_g,
                          int NB, int E) {
    __shared__ int hist[512];
    int t = threadIdx.x;
    hist[t] = 0;
    __syncthreads();
    int nvec = E >> 2;
    const int4* d4 = (const int4*)dst;
    for (int v = blockIdx.x * 512 + t; v < nvec; v += CNT_BLOCKS * 512) {
        int4 d = d4[v];
        atomicAdd(&hist[d.x >> RBITS], 1);
        atomicAdd(&hist[d.y >> RBITS], 1);
        atomicAdd(&hist[d.z >> RBITS], 1);
        atomicAdd(&hist[d.w >> RBITS], 1);
    }
    if (blockIdx.x == 0 && t < (E & 3))
        atomicAdd(&hist[dst[(nvec << 2) + t] >> RBITS], 1);
    __syncthreads();
    if (t < NB) hist_g[blockIdx.x * NB + t] = hist[t];
}

// ---------------- step 2: reduce partials + exclusive scan + cursor init ----------------
__global__ void bin_scan(const int* __restrict__ hist_g, int* __restrict__ bin_start,
                         int* __restrict__ bin_cursor, int NB) {
    __shared__ int s[512];
    int t = threadIdx.x;
    int v = 0;
    if (t < NB) {
        for (int k = 0; k < CNT_BLOCKS; ++k) v += hist_g[k * NB + t];
        bin_cursor[t] = 0;
    }
    s[t] = v;
    __syncthreads();
    for (int d = 1; d < 512; d <<= 1) {
        int a = (t >= d) ? s[t - d] : 0;
        __syncthreads();
        s[t] += a;
        __syncthreads();
    }
    if (t < NB) bin_start[t] = s[t] - v;       // exclusive
    if (t == NB - 1) bin_start[NB] = s[t];     // total = E
}

// ---------------- step 3: partition edges into bins (LDS staging) ----------------
#define SC_T 512
#define SC_K 8
#define SC_E (SC_T * SC_K)   // 4096 edges per block
__global__ void bin_scatter(const int* __restrict__ src, const int* __restrict__ dst,
                            const float* __restrict__ w, int* __restrict__ bin_cursor,
                            const int* __restrict__ bin_start,
                            int* __restrict__ bp, float* __restrict__ bw,
                            int NB, int E) {
    __shared__ int hist[512];
    __shared__ int offs[512];               // inclusive scan of hist
    __shared__ int base[512];               // global write base per bin
    __shared__ int stage_p[SC_E];
    __shared__ float stage_w[SC_E];
    __shared__ unsigned short stage_b[SC_E]; // bin id per staged slot
    int t = threadIdx.x;
    hist[t] = 0;
    __syncthreads();
    int e0 = blockIdx.x * SC_E;
    int nE = E - e0; if (nE > SC_E) nE = SC_E;

    int myBin[SC_K], myRank[SC_K], myPack[SC_K];
    float myW[SC_K];
#pragma unroll
    for (int k = 0; k < SC_K; ++k) {
        int idx = t + k * SC_T;
        if (idx < nE) {
            int e = e0 + idx;
            int d = dst[e];
            int b = d >> RBITS;
            myBin[k] = b;
            myPack[k] = (src[e] << RBITS) | (d & (RNODES - 1));
            myW[k] = w[e];
            myRank[k] = atomicAdd(&hist[b], 1);
        }
    }
    __syncthreads();
    offs[t] = hist[t];
    __syncthreads();
    for (int d = 1; d < 512; d <<= 1) {
        int a = (t >= d) ? offs[t - d] : 0;
        __syncthreads();
        offs[t] += a;
        __syncthreads();
    }
    if (t < NB && hist[t]) base[t] = bin_start[t] + atomicAdd(&bin_cursor[t], hist[t]);
#pragma unroll
    for (int k = 0; k < SC_K; ++k) {
        int idx = t + k * SC_T;
        if (idx < nE) {
            int b = myBin[k];
            int pos = (offs[b] - hist[b]) + myRank[k];
            stage_p[pos] = myPack[k];
            stage_w[pos] = myW[k];
            stage_b[pos] = (unsigned short)b;
        }
    }
    __syncthreads();
    for (int p = t; p < nE; p += SC_T) {
        int b = stage_b[p];
        int g = base[b] + (p - (offs[b] - hist[b]));
        bp[g] = stage_p[p];
        bw[g] = stage_w[p];
    }
}

// ---------------- step 4a: per-bin degree histogram -> row_beg / row_cnt / dinv ----------------
__global__ void deg_csr(const int* __restrict__ bp, const float* __restrict__ bw,
                        const int* __restrict__ bin_start,
                        int* __restrict__ row_beg, int* __restrict__ row_cnt,
                        float* __restrict__ dinv, int N) {
    __shared__ int cnt[RNODES];
    __shared__ float wsum[RNODES];
    __shared__ int starts[RNODES];
    int b = blockIdx.x;
    int t = threadIdx.x;   // 512
    if (t < RNODES) { cnt[t] = 0; wsum[t] = 0.f; }
    __syncthreads();
    int beg = bin_start[b], end = bin_start[b + 1];
    for (int e = beg + t; e < end; e += 512) {
        int off = bp[e] & (RNODES - 1);
        atomicAdd(&cnt[off], 1);
        atomicAdd(&wsum[off], bw[e]);
    }
    __syncthreads();
    if (t < RNODES) starts[t] = cnt[t];
    __syncthreads();
    for (int d = 1; d < RNODES; d <<= 1) {
        int a = 0;
        if (t < RNODES && t >= d) a = starts[t - d];
        __syncthreads();
        if (t < RNODES) starts[t] += a;
        __syncthreads();
    }
    if (t < RNODES) {
        int node = (b << RBITS) + t;
        if (node < N) {
            row_beg[node] = beg + (starts[t] - cnt[t]);
            row_cnt[node] = cnt[t];
            dinv[node] = rsqrtf(wsum[t] + 1.0f);   // +1 = self-loop weight
        }
    }
}

// ---------------- step 4b: scatter into dense CSR with dinv[src] folded ----------------
__global__ void csr_scatter(const int* __restrict__ bp, const float* __restrict__ bw,
                            const int* __restrict__ bin_start, const int* __restrict__ row_beg,
                            const float* __restrict__ dinv, uint2* __restrict__ ew, int N) {
    __shared__ int cur[RNODES];
    int b = blockIdx.x;
    int t = threadIdx.x;   // 512
    if (t < RNODES) {
        int node = (b << RBITS) + t;
        cur[t] = (node < N) ? row_beg[node] : 0;
    }
    __syncthreads();
    int beg = bin_start[b], end = bin_start[b + 1];
    for (int e = beg + t; e < end; e += 512) {
        int p = bp[e];
        int s = p >> RBITS;
        int slot = atomicAdd(&cur[p & (RNODES - 1)], 1);
        uint2 v;
        v.x = (unsigned)s;
        v.y = __float_as_uint(bw[e] * dinv[s]);   // fold dinv[src] once, here
        ew[slot] = v;
    }
}

// ---------------- MFMA GEMMs ----------------
// H1[N x 64] bf16 = X[N x 64] fp32 @ W[64 x 64] fp32   (split-bf16 3-product)
__global__ __launch_bounds__(256) void gemm1_mfma(const float* __restrict__ X,
                                                  const float* __restrict__ W,
                                                  unsigned short* __restrict__ H, int N) {
    int lane = threadIdx.x & 63;
    int wv = threadIdx.x >> 6;
    int quad = lane >> 4;
    int col = lane & 15;

    bf16x8 Bh[4][2], Bl[4][2];
#pragma unroll
    for (int nt = 0; nt < 4; ++nt)
#pragma unroll
        for (int kh = 0; kh < 2; ++kh)
#pragma unroll
            for (int j = 0; j < 8; ++j) {
                float wval = W[(kh * 32 + quad * 8 + j) * 64 + nt * 16 + col];
                unsigned hb = f2bf(wval);
                Bh[nt][kh][j] = (short)hb;
                Bl[nt][kh][j] = (short)f2bf(wval - bf2f(hb));
            }

#pragma unroll
    for (int rt = 0; rt < 4; ++rt) {
        int rb = blockIdx.x * 256 + wv * 64 + rt * 16;
        if (rb >= N) break;                       // wave-uniform
        int arow = rb + col;
        bf16x8 Ah[2], Al[2];
#pragma unroll
        for (int kh = 0; kh < 2; ++kh) {
            float xv[8];
            if (arow < N) {
                const float4* p = (const float4*)(X + (size_t)arow * 64 + kh * 32 + quad * 8);
                float4 f0 = p[0], f1 = p[1];
                xv[0] = f0.x; xv[1] = f0.y; xv[2] = f0.z; xv[3] = f0.w;
                xv[4] = f1.x; xv[5] = f1.y; xv[6] = f1.z; xv[7] = f1.w;
            } else {
#pragma unroll
                for (int j = 0; j < 8; ++j) xv[j] = 0.f;
            }
#pragma unroll
            for (int j = 0; j < 8; ++j) {
                unsigned hb = f2bf(xv[j]);
                Ah[kh][j] = (short)hb;
                Al[kh][j] = (short)f2bf(xv[j] - bf2f(hb));
            }
        }
        f32x4 acc[4] = {{0,0,0,0},{0,0,0,0},{0,0,0,0},{0,0,0,0}};
#pragma unroll
        for (int nt = 0; nt < 4; ++nt)
#pragma unroll
            for (int kh = 0; kh < 2; ++kh) {
                acc[nt] = __builtin_amdgcn_mfma_f32_16x16x32_bf16(Ah[kh], Bh[nt][kh], acc[nt], 0, 0, 0);
                acc[nt] = __builtin_amdgcn_mfma_f32_16x16x32_bf16(Al[kh], Bh[nt][kh], acc[nt], 0, 0, 0);
                acc[nt] = __builtin_amdgcn_mfma_f32_16x16x32_bf16(Ah[kh], Bl[nt][kh], acc[nt], 0, 0, 0);
            }
#pragma unroll
        for (int nt = 0; nt < 4; ++nt)
#pragma unroll
            for (int r = 0; r < 4; ++r) {
                int row = rb + quad * 4 + r;
                if (row < N)
                    H[(size_t)row * 64 + nt * 16 + col] = (unsigned short)f2bf(acc[nt][r]);
            }
    }
}

// H2[N x 32] bf16 = Xb[N x 64] bf16 (relu already applied) @ W[64 x 32] fp32
// A is exact bf16 -> only 2 products (A*Bh + A*Bl).
__global__ __launch_bounds__(256) void gemm2_mfma(const unsigned short* __restrict__ Xb,
                                                  const float* __restrict__ W,
                                                  unsigned short* __restrict__ H, int N) {
    int lane = threadIdx.x & 63;
    int wv = threadIdx.x >> 6;
    int quad = lane >> 4;
    int col = lane & 15;

    bf16x8 Bh[2][2], Bl[2][2];
#pragma unroll
    for (int nt = 0; nt < 2; ++nt)
#pragma unroll
        for (int kh = 0; kh < 2; ++kh)
#pragma unroll
            for (int j = 0; j < 8; ++j) {
                float wval = W[(kh * 32 + quad * 8 + j) * 32 + nt * 16 + col];
                unsigned hb = f2bf(wval);
                Bh[nt][kh][j] = (short)hb;
                Bl[nt][kh][j] = (short)f2bf(wval - bf2f(hb));
            }

#pragma unroll
    for (int rt = 0; rt < 4; ++rt) {
        int rb = blockIdx.x * 256 + wv * 64 + rt * 16;
        if (rb >= N) break;
        int arow = rb + col;
        bf16x8 A[2];
#pragma unroll
        for (int kh = 0; kh < 2; ++kh) {
            if (arow < N) {
                const bf16x8* p = (const bf16x8*)(Xb + (size_t)arow * 64 + kh * 32 + quad * 8);
                A[kh] = *p;                        // already bf16 — exact
            } else {
                A[kh] = bf16x8{0,0,0,0,0,0,0,0};
            }
        }
        f32x4 acc[2] = {{0,0,0,0},{0,0,0,0}};
#pragma unroll
        for (int nt = 0; nt < 2; ++nt)
#pragma unroll
            for (int kh = 0; kh < 2; ++kh) {
                acc[nt] = __builtin_amdgcn_mfma_f32_16x16x32_bf16(A[kh], Bh[nt][kh], acc[nt], 0, 0, 0);
                acc[nt] = __builtin_amdgcn_mfma_f32_16x16x32_bf16(A[kh], Bl[nt][kh], acc[nt], 0, 0, 0);
            }
#pragma unroll
        for (int nt = 0; nt < 2; ++nt)
#pragma unroll
            for (int r = 0; r < 4; ++r) {
                int row = rb + quad * 4 + r;
                if (row < N)
                    H[(size_t)row * 32 + nt * 16 + col] = (unsigned short)f2bf(acc[nt][r]);
            }
    }
}

// ---------------- aggregation: 1 node per 8-lane group, packed uint2 edges ----------------
// Layer 1: bf16 h1 in, bf16 out (relu fused). Edge coeff = w*dinv[src] pre-folded.
__global__ void aggregate64(const unsigned* __restrict__ h, const int* __restrict__ row_beg,
                            const int* __restrict__ row_cnt, const uint2* __restrict__ ew,
                            const float* __restrict__ dinv, const float* __restrict__ b,
                            unsigned* __restrict__ outb, int N) {
    int t = threadIdx.x;
    int c = t & 7;                       // uint4 index in row (8 ch per lane)
    int i = blockIdx.x * 64 + (t >> 3);  // node per 8-lane group
    if (i >= N) return;
    int e = row_beg[i];
    int end = e + row_cnt[i];
    const uint4* h4 = (const uint4*)h;
    float acc[8];
#pragma unroll
    for (int j = 0; j < 8; ++j) acc[j] = 0.f;
    for (; e + 3 < end; e += 4) {
        uint2 e0 = ew[e], e1 = ew[e + 1], e2 = ew[e + 2], e3 = ew[e + 3];
        float n0 = __uint_as_float(e0.y);
        float n1 = __uint_as_float(e1.y);
        float n2 = __uint_as_float(e2.y);
        float n3 = __uint_as_float(e3.y);
        uint4 v0 = h4[(size_t)e0.x * 8 + c];
        uint4 v1 = h4[(size_t)e1.x * 8 + c];
        uint4 v2 = h4[(size_t)e2.x * 8 + c];
        uint4 v3 = h4[(size_t)e3.x * 8 + c];
        acc[0] += n0 * bf_lo(v0.x) + n1 * bf_lo(v1.x) + n2 * bf_lo(v2.x) + n3 * bf_lo(v3.x);
        acc[1] += n0 * bf_hi(v0.x) + n1 * bf_hi(v1.x) + n2 * bf_hi(v2.x) + n3 * bf_hi(v3.x);
        acc[2] += n0 * bf_lo(v0.y) + n1 * bf_lo(v1.y) + n2 * bf_lo(v2.y) + n3 * bf_lo(v3.y);
        acc[3] += n0 * bf_hi(v0.y) + n1 * bf_hi(v1.y) + n2 * bf_hi(v2.y) + n3 * bf_hi(v3.y);
        acc[4] += n0 * bf_lo(v0.z) + n1 * bf_lo(v1.z) + n2 * bf_lo(v2.z) + n3 * bf_lo(v3.z);
        acc[5] += n0 * bf_hi(v0.z) + n1 * bf_hi(v1.z) + n2 * bf_hi(v2.z) + n3 * bf_hi(v3.z);
        acc[6] += n0 * bf_lo(v0.w) + n1 * bf_lo(v1.w) + n2 * bf_lo(v2.w) + n3 * bf_lo(v3.w);
        acc[7] += n0 * bf_hi(v0.w) + n1 * bf_hi(v1.w) + n2 * bf_hi(v2.w) + n3 * bf_hi(v3.w);
    }
    for (; e < end; ++e) {
        uint2 e0 = ew[e];
        float n0 = __uint_as_float(e0.y);
        uint4 v0 = h4[(size_t)e0.x * 8 + c];
        acc[0] += n0 * bf_lo(v0.x);
        acc[1] += n0 * bf_hi(v0.x);
        acc[2] += n0 * bf_lo(v0.y);
        acc[3] += n0 * bf_hi(v0.y);
        acc[4] += n0 * bf_lo(v0.z);
        acc[5] += n0 * bf_hi(v0.z);
        acc[6] += n0 * bf_lo(v0.w);
        acc[7] += n0 * bf_hi(v0.w);
    }
    float di = dinv[i];
    uint4 hv = h4[(size_t)i * 8 + c];
    float hs[8] = {bf_lo(hv.x), bf_hi(hv.x), bf_lo(hv.y), bf_hi(hv.y),
                   bf_lo(hv.z), bf_hi(hv.z), bf_lo(hv.w), bf_hi(hv.w)};
    float4 b0 = ((const float4*)b)[c * 2];
    float4 b1 = ((const float4*)b)[c * 2 + 1];
    float o[8];
    o[0] = b0.x + di * (di * hs[0] + acc[0]);
    o[1] = b0.y + di * (di * hs[1] + acc[1]);
    o[2] = b0.z + di * (di * hs[2] + acc[2]);
    o[3] = b0.w + di * (di * hs[3] + acc[3]);
    o[4] = b1.x + di * (di * hs[4] + acc[4]);
    o[5] = b1.y + di * (di * hs[5] + acc[5]);
    o[6] = b1.z + di * (di * hs[6] + acc[6]);
    o[7] = b1.w + di * (di * hs[7] + acc[7]);
#pragma unroll
    for (int j = 0; j < 8; ++j) o[j] = fmaxf(o[j], 0.f);   // fused relu (out1 only feeds gemm2)
    uint4 ov;
    ov.x = pack2(o[0], o[1]);
    ov.y = pack2(o[2], o[3]);
    ov.z = pack2(o[4], o[5]);
    ov.w = pack2(o[6], o[7]);
    ((uint4*)outb)[(size_t)i * 8 + c] = ov;
}

// Layer 2: bf16 h2 in, fp32 final out. 1 node per 4-lane group.
__global__ void aggregate32(const unsigned* __restrict__ h, const int* __restrict__ row_beg,
                            const int* __restrict__ row_cnt, const uint2* __restrict__ ew,
                            const float* __restrict__ dinv, const float* __restrict__ b,
                            float* __restrict__ out, int N) {
    int t = threadIdx.x;
    int c = t & 3;                        // uint4 index in row (8 ch per lane)
    int i = blockIdx.x * 128 + (t >> 2);  // node per 4-lane group
    if (i >= N) return;
    int e = row_beg[i];
    int end = e + row_cnt[i];
    const uint4* h4 = (const uint4*)h;
    float acc[8];
#pragma unroll
    for (int j = 0; j < 8; ++j) acc[j] = 0.f;
    for (; e + 3 < end; e += 4) {
        uint2 e0 = ew[e], e1 = ew[e + 1], e2 = ew[e + 2], e3 = ew[e + 3];
        float n0 = __uint_as_float(e0.y);
        float n1 = __uint_as_float(e1.y);
        float n2 = __uint_as_float(e2.y);
        float n3 = __uint_as_float(e3.y);
        uint4 v0 = h4[(size_t)e0.x * 4 + c];
        uint4 v1 = h4[(size_t)e1.x * 4 + c];
        uint4 v2 = h4[(size_t)e2.x * 4 + c];
        uint4 v3 = h4[(size_t)e3.x * 4 + c];
        acc[0] += n0 * bf_lo(v0.x) + n1 * bf_lo(v1.x) + n2 * bf_lo(v2.x) + n3 * bf_lo(v3.x);
        acc[1] += n0 * bf_hi(v0.x) + n1 * bf_hi(v1.x) + n2 * bf_hi(v2.x) + n3 * bf_hi(v3.x);
        acc[2] += n0 * bf_lo(v0.y) + n1 * bf_lo(v1.y) + n2 * bf_lo(v2.y) + n3 * bf_lo(v3.y);
        acc[3] += n0 * bf_hi(v0.y) + n1 * bf_hi(v1.y) + n2 * bf_hi(v2.y) + n3 * bf_hi(v3.y);
        acc[4] += n0 * bf_lo(v0.z) + n1 * bf_lo(v1.z) + n2 * bf_lo(v2.z) + n3 * bf_lo(v3.z);
        acc[5] += n0 * bf_hi(v0.z) + n1 * bf_hi(v1.z) + n2 * bf_hi(v2.z) + n3 * bf_hi(v3.z);
        acc[6] += n0 * bf_lo(v0.w) + n1 * bf_lo(v1.w) + n2 * bf_lo(v2.w) + n3 * bf_lo(v3.w);
        acc[7] += n0 * bf_hi(v0.w) + n1 * bf_hi(v1.w) + n2 * bf_hi(v2.w) + n3 * bf_hi(v3.w);
    }
    for (; e < end; ++e) {
        uint2 e0 = ew[e];
        float n0 = __uint_as_float(e0.y);
        uint4 v0 = h4[(size_t)e0.x * 4 + c];
        acc[0] += n0 * bf_lo(v0.x);
        acc[1] += n0 * bf_hi(v0.x);
        acc[2] += n0 * bf_lo(v0.y);
        acc[3] += n0 * bf_hi(v0.y);
        acc[4] += n0 * bf_lo(v0.z);
        acc[5] += n0 * bf_hi(v0.z);
        acc[6] += n0 * bf_lo(v0.w);
        acc[7] += n0 * bf_hi(v0.w);
    }
    float di = dinv[i];
    uint4 hv = h4[(size_t)i * 4 + c];
    float hs[8] = {bf_lo(hv.x), bf_hi(hv.x), bf_lo(hv.y), bf_hi(hv.y),
                   bf_lo(hv.z), bf_hi(hv.z), bf_lo(hv.w), bf_hi(hv.w)};
    float4 b0 = ((const float4*)b)[c * 2];
    float4 b1 = ((const float4*)b)[c * 2 + 1];
    float4 o0, o1;
    o0.x = b0.x + di * (di * hs[0] + acc[0]);
    o0.y = b0.y + di * (di * hs[1] + acc[1]);
    o0.z = b0.z + di * (di * hs[2] + acc[2]);
    o0.w = b0.w + di * (di * hs[3] + acc[3]);
    o1.x = b1.x + di * (di * hs[4] + acc[4]);
    o1.y = b1.y + di * (di * hs[5] + acc[5]);
    o1.z = b1.z + di * (di * hs[6] + acc[6]);
    o1.w = b1.w + di * (di * hs[7] + acc[7]);
    float4* op = (float4*)(out + (size_t)i * 32 + c * 8);
    op[0] = o0;
    op[1] = o1;
}

extern "C" void kernel_launch(void* const* d_in, const int* in_sizes, int n_in,
                              void* d_out, int out_size, void* d_ws, size_t ws_size,
                              hipStream_t stream) {
    const float* x  = (const float*)d_in[0];
    const int* eidx = (const int*)d_in[1];      // int64 in reference -> int32 on device
    const float* w  = (const float*)d_in[2];
    const float* W1 = (const float*)d_in[3];
    const float* b1 = (const float*)d_in[4];
    const float* W2 = (const float*)d_in[5];
    const float* b2 = (const float*)d_in[6];
    float* out = (float*)d_out;

    const int E = in_sizes[2];
    const int N = in_sizes[0] / 64;
    const int* src = eidx;
    const int* dst = eidx + E;
    const int NB = ceil_div(N, RNODES);          // 391 bins (must be <= 512)

    // workspace carve-up (256B-aligned)
    char* ws = (char*)d_ws;
    size_t off = 0;
    auto alloc = [&](size_t bytes) -> void* {
        void* p = ws + off;
        off = (off + bytes + 255) & ~(size_t)255;
        return p;
    };
    int*      hist_g     = (int*)alloc((size_t)CNT_BLOCKS * NB * 4);
    int*      bin_cursor = (int*)alloc((size_t)NB * 4);
    int*      bin_start  = (int*)alloc((size_t)(NB + 1) * 4);
    int*      bp         = (int*)alloc((size_t)E * 4);      // binned packed (src<<8)|dstoff
    float*    bw         = (float*)alloc((size_t)E * 4);    // binned weights
    uint2*    ew         = (uint2*)alloc((size_t)E * 8);    // dense CSR {src, w*dinv[src]}
    int*      row_beg    = (int*)alloc((size_t)N * 4);
    int*      row_cnt    = (int*)alloc((size_t)N * 4);
    float*    dinv       = (float*)alloc((size_t)N * 4);
    unsigned* h1         = (unsigned*)alloc((size_t)N * 32 * 4);  // bf16 N x 64
    unsigned* out1b      = (unsigned*)alloc((size_t)N * 32 * 4);  // bf16 relu(out1), N x 64
    unsigned* h2         = (unsigned*)alloc((size_t)N * 16 * 4);  // bf16 N x 32

    // build (no per-edge global atomics anywhere)
    bin_count<<<CNT_BLOCKS, 512, 0, stream>>>(dst, hist_g, NB, E);
    bin_scan<<<1, 512, 0, stream>>>(hist_g, bin_start, bin_cursor, NB);
    bin_scatter<<<ceil_div(E, SC_E), SC_T, 0, stream>>>(src, dst, w, bin_cursor, bin_start,
                                                        bp, bw, NB, E);
    deg_csr<<<NB, 512, 0, stream>>>(bp, bw, bin_start, row_beg, row_cnt, dinv, N);
    csr_scatter<<<NB, 512, 0, stream>>>(bp, bw, bin_start, row_beg, dinv, ew, N);

    // layer 1 (MFMA gemm -> bf16 table; aggregate -> bf16 relu'd out1)
    gemm1_mfma<<<ceil_div(N, 256), 256, 0, stream>>>(x, W1, (unsigned short*)h1, N);
    aggregate64<<<ceil_div(N, 64), 512, 0, stream>>>(h1, row_beg, row_cnt, ew, dinv, b1, out1b, N);

    // layer 2 (bf16-A MFMA gemm -> bf16 table; aggregate -> fp32 out)
    gemm2_mfma<<<ceil_div(N, 256), 256, 0, stream>>>((const unsigned short*)out1b, W2,
                                                     (unsigned short*)h2, N);
    aggregate32<<<ceil_div(N, 128), 512, 0, stream>>>(h2, row_beg, row_cnt, ew, dinv, b2, out, N);
}